// Round 6
// baseline (4040.050 us; speedup 1.0000x reference)
//
#include <hip/hip_runtime.h>
#include <hip/hip_bf16.h>
#include <math.h>

// ---- dims ----
constexpr int B  = 64;
constexpr int S  = 50;
constexpr int W  = 30;
constexpr int E  = 128;
constexpr int H  = 128;
constexpr int G4 = 4 * H;      // 512
constexpr int NW = B * S;      // 3200 word sequences
constexpr int NSEQ_W = 8;      // word seqs per block
constexpr int NSEQ_S = 4;      // doc seqs per block
constexpr int NSEQ_G = 8;      // rows per block in sl gin GEMM

// ---- intermediates as module-scope device globals (no d_ws dependence) ----
__device__ float g_wl_h[(size_t)NW * W * 256];  // 98.3 MB fp32
__device__ float g_sent [(size_t)NW * 256];     // 3.28 MB
__device__ float g_gin_f[(size_t)NW * 512];     // 6.55 MB
__device__ float g_gin_b[(size_t)NW * 512];     // 6.55 MB
__device__ float g_sl_h [(size_t)B * S * 256];  // 3.28 MB
__device__ float g_doc  [(size_t)B * 256];      // 64 KB

// ---- helpers ----
__device__ __forceinline__ float sigf(float x) { return 1.0f / (1.0f + expf(-x)); }
__device__ __forceinline__ float dot4(float4 a, float4 b) {
    return fmaf(a.x, b.x, fmaf(a.y, b.y, fmaf(a.z, b.z, a.w * b.w)));
}

// ============================================================
// K1: word-level BiLSTM, persistent over T=30 steps.
// 1-D grid: blockIdx.x = sblk*2 + dir (800 blocks), block 256.
// All inputs fp32 (proven R1: bf16-interpretation -> NaN).
// out: g_wl_h fp32 [NW][W][256], fwd [0:128) bwd [128:256). LDS 28 KB.
// ============================================================
__global__ __launch_bounds__(256) void k_word_lstm(
    const int* __restrict__ ids, const float* __restrict__ emb,
    const float* __restrict__ Wih_f, const float* __restrict__ Whh_f,
    const float* __restrict__ bih_f, const float* __restrict__ bhh_f,
    const float* __restrict__ Wih_b, const float* __restrict__ Whh_b,
    const float* __restrict__ bih_b, const float* __restrict__ bhh_b)
{
    const int dir = blockIdx.x & 1;
    const int s0  = (blockIdx.x >> 1) * NSEQ_W;
    const float* Wih = dir ? Wih_b : Wih_f;
    const float* Whh = dir ? Whh_b : Whh_f;
    const float* bih = dir ? bih_b : bih_f;
    const float* bhh = dir ? bhh_b : bhh_f;

    __shared__ float xs[NSEQ_W][E];
    __shared__ float hs[NSEQ_W][H];
    __shared__ float cs[NSEQ_W][H];
    __shared__ float gs[NSEQ_W][G4];

    const int tid = threadIdx.x;
    for (int i = tid; i < NSEQ_W * H; i += 256) { (&hs[0][0])[i] = 0.f; (&cs[0][0])[i] = 0.f; }
    const int g0 = tid, g1 = tid + 256;
    const float bv0 = bih[g0] + bhh[g0];
    const float bv1 = bih[g1] + bhh[g1];
    const float* wih0 = &Wih[g0 * E]; const float* wih1 = &Wih[g1 * E];
    const float* whh0 = &Whh[g0 * H]; const float* whh1 = &Whh[g1 * H];
    __syncthreads();

    for (int st = 0; st < W; ++st) {
        const int t = dir ? (W - 1 - st) : st;
        {
            const int s  = tid >> 5;
            const int k4 = (tid & 31) * 4;
            const int id = ids[(s0 + s) * W + t];
            *(float4*)&xs[s][k4] = *(const float4*)&emb[(size_t)id * E + k4];
        }
        __syncthreads();

        float acc0[NSEQ_W], acc1[NSEQ_W];
        #pragma unroll
        for (int s = 0; s < NSEQ_W; ++s) { acc0[s] = 0.f; acc1[s] = 0.f; }
        for (int k = 0; k < E; k += 4) {
            float4 wa = *(const float4*)(wih0 + k);
            float4 wb = *(const float4*)(wih1 + k);
            float4 va = *(const float4*)(whh0 + k);
            float4 vb = *(const float4*)(whh1 + k);
            #pragma unroll
            for (int s = 0; s < NSEQ_W; ++s) {
                float4 xv = *(const float4*)&xs[s][k];
                float4 hv = *(const float4*)&hs[s][k];
                acc0[s] += dot4(wa, xv) + dot4(va, hv);
                acc1[s] += dot4(wb, xv) + dot4(vb, hv);
            }
        }
        #pragma unroll
        for (int s = 0; s < NSEQ_W; ++s) { gs[s][g0] = acc0[s] + bv0; gs[s][g1] = acc1[s] + bv1; }
        __syncthreads();

        #pragma unroll
        for (int r = 0; r < 4; ++r) {
            const int j = tid & 127;
            const int s = (tid >> 7) + r * 2;
            float gi = gs[s][j], gf = gs[s][j + H], gg = gs[s][j + 2 * H], go = gs[s][j + 3 * H];
            float c = sigf(gf) * cs[s][j] + sigf(gi) * tanhf(gg);
            float h = sigf(go) * tanhf(c);
            cs[s][j] = c; hs[s][j] = h;
            g_wl_h[((size_t)(s0 + s) * W + t) * 256 + dir * H + j] = h;
        }
        __syncthreads();
    }
}

// ============================================================
// K2: word attention pool, CHUNKED (CH=10 -> 10 KB LDS), fp32 h.
// grid NW (1-D), block 128. Writes g_sent.
// ============================================================
template <int T, int CH>
__global__ __launch_bounds__(128) void k_attn_pool_word(
    const int* __restrict__ ids,
    const float* __restrict__ W1, const float* __restrict__ b1,
    const float* __restrict__ W2, const float* __restrict__ b2)
{
    const int n = blockIdx.x;
    __shared__ float hsh[CH][256];
    __shared__ float part[2][T];
    __shared__ float wsh[T];
    const int tid = threadIdx.x;
    const float* src = g_wl_h + (size_t)n * T * 256;
    const float b1v = b1[tid];
    const float w2v = W2[tid];
    const int wave = tid >> 6, lane = tid & 63;

    for (int c = 0; c < T; c += CH) {
        __syncthreads();
        for (int i = tid * 4; i < CH * 256; i += 512)
            *(float4*)&(&hsh[0][0])[i] = *(const float4*)&src[(size_t)c * 256 + i];
        __syncthreads();
        float acc[CH];
        #pragma unroll
        for (int u = 0; u < CH; ++u) acc[u] = 0.f;
        const float* w1p = &W1[tid * 256];
        for (int k = 0; k < 256; k += 4) {
            float4 w4 = *(const float4*)(w1p + k);
            #pragma unroll
            for (int u = 0; u < CH; ++u)
                acc[u] += dot4(w4, *(const float4*)&hsh[u][k]);
        }
        #pragma unroll
        for (int u = 0; u < CH; ++u) {
            float v = w2v * tanhf(acc[u] + b1v);
            #pragma unroll
            for (int off = 32; off > 0; off >>= 1) v += __shfl_down(v, off, 64);
            if (lane == 0) part[wave][c + u] = v;
        }
    }
    __syncthreads();

    if (tid < T) {
        bool valid = (ids[n * T + tid] != 0);
        wsh[tid] = valid ? (part[0][tid] + part[1][tid] + b2[0]) : -INFINITY;
    }
    __syncthreads();
    if (tid == 0) {
        float m = -INFINITY;
        for (int t = 0; t < T; ++t) m = fmaxf(m, wsh[t]);
        float sum = 0.f;
        for (int t = 0; t < T; ++t) sum += (wsh[t] == -INFINITY) ? 0.f : expf(wsh[t] - m);
        const float inv = (sum > 0.f) ? 1.f / sum : 0.f;
        for (int t = 0; t < T; ++t) wsh[t] = (wsh[t] == -INFINITY) ? 0.f : expf(wsh[t] - m) * inv;
    }

    float o0 = 0.f, o1 = 0.f;
    for (int c = 0; c < T; c += CH) {
        __syncthreads();
        for (int i = tid * 4; i < CH * 256; i += 512)
            *(float4*)&(&hsh[0][0])[i] = *(const float4*)&src[(size_t)c * 256 + i];
        __syncthreads();
        #pragma unroll
        for (int u = 0; u < CH; ++u) {
            float w = wsh[c + u];
            o0 += w * hsh[u][tid];
            o1 += w * hsh[u][tid + 128];
        }
    }
    g_sent[(size_t)n * 256 + tid] = o0;
    g_sent[(size_t)n * 256 + tid + 128] = o1;
}

// ============================================================
// K3: sentence LSTM input projection: gin = sent @ Wih^T + bih + bhh
// 1-D grid: blockIdx.x = rblk*2 + dir (800 blocks), block 256.
// ============================================================
__global__ __launch_bounds__(256) void k_sl_gin(
    const float* __restrict__ Wih_f, const float* __restrict__ bih_f, const float* __restrict__ bhh_f,
    const float* __restrict__ Wih_b, const float* __restrict__ bih_b, const float* __restrict__ bhh_b)
{
    const int dir = blockIdx.x & 1;
    const float* Wih = dir ? Wih_b : Wih_f;
    const float* bih = dir ? bih_b : bih_f;
    const float* bhh = dir ? bhh_b : bhh_f;
    float* gin = dir ? g_gin_b : g_gin_f;
    const int r0 = (blockIdx.x >> 1) * NSEQ_G;

    __shared__ float xs[NSEQ_G][256];
    const int tid = threadIdx.x;
    for (int i = tid * 4; i < NSEQ_G * 256; i += 1024)
        *(float4*)&(&xs[0][0])[i] = *(const float4*)&g_sent[(size_t)r0 * 256 + i];
    __syncthreads();

    const int g0 = tid, g1 = tid + 256;
    float acc0[NSEQ_G], acc1[NSEQ_G];
    #pragma unroll
    for (int s = 0; s < NSEQ_G; ++s) { acc0[s] = 0.f; acc1[s] = 0.f; }
    const float* w0 = &Wih[g0 * 256]; const float* w1 = &Wih[g1 * 256];
    for (int k = 0; k < 256; k += 4) {
        float4 wa = *(const float4*)(w0 + k);
        float4 wb = *(const float4*)(w1 + k);
        #pragma unroll
        for (int s = 0; s < NSEQ_G; ++s) {
            float4 xv = *(const float4*)&xs[s][k];
            acc0[s] += dot4(wa, xv);
            acc1[s] += dot4(wb, xv);
        }
    }
    const float bv0 = bih[g0] + bhh[g0];
    const float bv1 = bih[g1] + bhh[g1];
    #pragma unroll
    for (int s = 0; s < NSEQ_G; ++s) {
        gin[(size_t)(r0 + s) * 512 + g0] = acc0[s] + bv0;
        gin[(size_t)(r0 + s) * 512 + g1] = acc1[s] + bv1;
    }
}

// ============================================================
// K4: sentence BiLSTM, persistent over T=50.
// 1-D grid: blockIdx.x = bblk*2 + dir (32 blocks), block 256. LDS 12 KB.
// ============================================================
__global__ __launch_bounds__(256) void k_sent_lstm(
    const float* __restrict__ Whh_f, const float* __restrict__ Whh_b)
{
    const int dir = blockIdx.x & 1;
    const float* gin = dir ? g_gin_b : g_gin_f;
    const float* Whh = dir ? Whh_b : Whh_f;
    const int b0 = (blockIdx.x >> 1) * NSEQ_S;

    __shared__ float hs[NSEQ_S][H];
    __shared__ float cs[NSEQ_S][H];
    __shared__ float gs[NSEQ_S][G4];
    const int tid = threadIdx.x;
    for (int i = tid; i < NSEQ_S * H; i += 256) { (&hs[0][0])[i] = 0.f; (&cs[0][0])[i] = 0.f; }
    const int g0 = tid, g1 = tid + 256;
    const float* w0 = &Whh[g0 * H]; const float* w1 = &Whh[g1 * H];
    __syncthreads();

    for (int st = 0; st < S; ++st) {
        const int t = dir ? (S - 1 - st) : st;
        float acc0[NSEQ_S], acc1[NSEQ_S];
        #pragma unroll
        for (int s = 0; s < NSEQ_S; ++s) {
            acc0[s] = gin[(size_t)((b0 + s) * S + t) * 512 + g0];
            acc1[s] = gin[(size_t)((b0 + s) * S + t) * 512 + g1];
        }
        for (int k = 0; k < H; k += 4) {
            float4 va = *(const float4*)(w0 + k);
            float4 vb = *(const float4*)(w1 + k);
            #pragma unroll
            for (int s = 0; s < NSEQ_S; ++s) {
                float4 hv = *(const float4*)&hs[s][k];
                acc0[s] += dot4(va, hv);
                acc1[s] += dot4(vb, hv);
            }
        }
        #pragma unroll
        for (int s = 0; s < NSEQ_S; ++s) { gs[s][g0] = acc0[s]; gs[s][g1] = acc1[s]; }
        __syncthreads();
        #pragma unroll
        for (int r = 0; r < 2; ++r) {
            const int j = tid & 127;
            const int s = (tid >> 7) + r * 2;
            float gi = gs[s][j], gf = gs[s][j + H], gg = gs[s][j + 2 * H], go = gs[s][j + 3 * H];
            float c = sigf(gf) * cs[s][j] + sigf(gi) * tanhf(gg);
            float h = sigf(go) * tanhf(c);
            cs[s][j] = c; hs[s][j] = h;
            g_sl_h[(size_t)((b0 + s) * S + t) * 256 + dir * H + j] = h;
        }
        __syncthreads();
    }
}

// ============================================================
// K5: document attention pool, CHUNKED (10 KB LDS), fp32 input.
// grid B (1-D), block 128. Writes g_doc.
// ============================================================
template <int T, int CH>
__global__ __launch_bounds__(128) void k_attn_pool_doc(
    const int* __restrict__ ids,
    const float* __restrict__ W1, const float* __restrict__ b1,
    const float* __restrict__ W2, const float* __restrict__ b2)
{
    const int n = blockIdx.x;
    __shared__ float hsh[CH][256];
    __shared__ float part[2][T];
    __shared__ float wsh[T];
    const int tid = threadIdx.x;
    const float* src = g_sl_h + (size_t)n * T * 256;
    const float b1v = b1[tid];
    const float w2v = W2[tid];
    const int wave = tid >> 6, lane = tid & 63;

    for (int c = 0; c < T; c += CH) {
        __syncthreads();
        for (int i = tid * 4; i < CH * 256; i += 512)
            *(float4*)&(&hsh[0][0])[i] = *(const float4*)&src[(size_t)c * 256 + i];
        __syncthreads();
        float acc[CH];
        #pragma unroll
        for (int u = 0; u < CH; ++u) acc[u] = 0.f;
        const float* w1p = &W1[tid * 256];
        for (int k = 0; k < 256; k += 4) {
            float4 w4 = *(const float4*)(w1p + k);
            #pragma unroll
            for (int u = 0; u < CH; ++u)
                acc[u] += dot4(w4, *(const float4*)&hsh[u][k]);
        }
        #pragma unroll
        for (int u = 0; u < CH; ++u) {
            float v = w2v * tanhf(acc[u] + b1v);
            #pragma unroll
            for (int off = 32; off > 0; off >>= 1) v += __shfl_down(v, off, 64);
            if (lane == 0) part[wave][c + u] = v;
        }
    }
    __syncthreads();

    if (tid < T) {
        bool valid = false;
        const int* ip = &ids[((size_t)n * T + tid) * W];
        for (int w = 0; w < W; ++w) valid |= (ip[w] != 0);
        wsh[tid] = valid ? (part[0][tid] + part[1][tid] + b2[0]) : -INFINITY;
    }
    __syncthreads();
    if (tid == 0) {
        float m = -INFINITY;
        for (int t = 0; t < T; ++t) m = fmaxf(m, wsh[t]);
        float sum = 0.f;
        for (int t = 0; t < T; ++t) sum += (wsh[t] == -INFINITY) ? 0.f : expf(wsh[t] - m);
        const float inv = (sum > 0.f) ? 1.f / sum : 0.f;
        for (int t = 0; t < T; ++t) wsh[t] = (wsh[t] == -INFINITY) ? 0.f : expf(wsh[t] - m) * inv;
    }

    float o0 = 0.f, o1 = 0.f;
    for (int c = 0; c < T; c += CH) {
        __syncthreads();
        for (int i = tid * 4; i < CH * 256; i += 512)
            *(float4*)&(&hsh[0][0])[i] = *(const float4*)&src[(size_t)c * 256 + i];
        __syncthreads();
        #pragma unroll
        for (int u = 0; u < CH; ++u) {
            float w = wsh[c + u];
            o0 += w * hsh[u][tid];
            o1 += w * hsh[u][tid + 128];
        }
    }
    g_doc[(size_t)n * 256 + tid] = o0;
    g_doc[(size_t)n * 256 + tid + 128] = o1;
}

// ============================================================
// K6: classifier. OUTPUT IS FP32 (reference returns float32 logits;
// harness: "bfloat16 -> __hip_bfloat16*, else float*").
// grid B, block 128.
// ============================================================
__global__ __launch_bounds__(128) void k_classifier(
    const float* __restrict__ W1, const float* __restrict__ b1,
    const float* __restrict__ W2, const float* __restrict__ b2,
    float* __restrict__ out /* [B][3] fp32 */)
{
    const int b = blockIdx.x;
    __shared__ float dsh[256];
    __shared__ float hsh[128];
    const int tid = threadIdx.x;
    if (tid < 64) *(float4*)&dsh[tid * 4] = *(const float4*)&g_doc[(size_t)b * 256 + tid * 4];
    __syncthreads();
    float acc = 0.f;
    const float* w1p = &W1[tid * 256];
    for (int k = 0; k < 256; k += 4) {
        float4 w4 = *(const float4*)(w1p + k);
        float4 d4 = *(const float4*)&dsh[k];
        acc += dot4(w4, d4);
    }
    hsh[tid] = fmaxf(acc + b1[tid], 0.f);
    __syncthreads();
    if (tid < 3) {
        float a = b2[tid];
        const float* w2p = &W2[tid * 128];
        for (int j = 0; j < 128; ++j) a += w2p[j] * hsh[j];
        out[b * 3 + tid] = a;
    }
}

// ============================================================
extern "C" void kernel_launch(void* const* d_in, const int* in_sizes, int n_in,
                              void* d_out, int out_size, void* d_ws, size_t ws_size,
                              hipStream_t stream) {
    // Inputs fp32 (proven R1), ids int32, OUTPUT fp32. d_ws unused.
    const int*   ids      = (const int*)d_in[0];
    const float* emb      = (const float*)d_in[1];
    const float* wl_Wih_f = (const float*)d_in[2];
    const float* wl_Whh_f = (const float*)d_in[3];
    const float* wl_bih_f = (const float*)d_in[4];
    const float* wl_bhh_f = (const float*)d_in[5];
    const float* wl_Wih_b = (const float*)d_in[6];
    const float* wl_Whh_b = (const float*)d_in[7];
    const float* wl_bih_b = (const float*)d_in[8];
    const float* wl_bhh_b = (const float*)d_in[9];
    const float* sl_Wih_f = (const float*)d_in[10];
    const float* sl_Whh_f = (const float*)d_in[11];
    const float* sl_bih_f = (const float*)d_in[12];
    const float* sl_bhh_f = (const float*)d_in[13];
    const float* sl_Wih_b = (const float*)d_in[14];
    const float* sl_Whh_b = (const float*)d_in[15];
    const float* sl_bih_b = (const float*)d_in[16];
    const float* sl_bhh_b = (const float*)d_in[17];
    const float* wa_W1 = (const float*)d_in[18];
    const float* wa_b1 = (const float*)d_in[19];
    const float* wa_W2 = (const float*)d_in[20];
    const float* wa_b2 = (const float*)d_in[21];
    const float* sa_W1 = (const float*)d_in[22];
    const float* sa_b1 = (const float*)d_in[23];
    const float* sa_W2 = (const float*)d_in[24];
    const float* sa_b2 = (const float*)d_in[25];
    const float* cl_W1 = (const float*)d_in[26];
    const float* cl_b1 = (const float*)d_in[27];
    const float* cl_W2 = (const float*)d_in[28];
    const float* cl_b2 = (const float*)d_in[29];

    k_word_lstm<<<NW / NSEQ_W * 2, 256, 0, stream>>>(
        ids, emb, wl_Wih_f, wl_Whh_f, wl_bih_f, wl_bhh_f,
        wl_Wih_b, wl_Whh_b, wl_bih_b, wl_bhh_b);

    k_attn_pool_word<W, 10><<<NW, 128, 0, stream>>>(ids, wa_W1, wa_b1, wa_W2, wa_b2);

    k_sl_gin<<<NW / NSEQ_G * 2, 256, 0, stream>>>(
        sl_Wih_f, sl_bih_f, sl_bhh_f, sl_Wih_b, sl_bih_b, sl_bhh_b);

    k_sent_lstm<<<B / NSEQ_S * 2, 256, 0, stream>>>(sl_Whh_f, sl_Whh_b);

    k_attn_pool_doc<S, 10><<<B, 128, 0, stream>>>(ids, sa_W1, sa_b1, sa_W2, sa_b2);

    k_classifier<<<B, 128, 0, stream>>>(cl_W1, cl_b1, cl_W2, cl_b2, (float*)d_out);
}

// Round 7
// 2700.683 us; speedup vs baseline: 1.4959x; 1.4959x over previous
//
#include <hip/hip_runtime.h>
#include <math.h>

// ---- dims ----
constexpr int B  = 64;
constexpr int S  = 50;
constexpr int W  = 30;
constexpr int E  = 128;
constexpr int H  = 128;
constexpr int G4 = 4 * H;      // 512
constexpr int NW = B * S;      // 3200 word sequences
constexpr int V  = 50000;      // vocab
constexpr int NSEQ_W = 4;      // word seqs per block (R7: 8->4 for occupancy)
constexpr int NSEQ_S = 4;      // doc seqs per block
constexpr int NSEQ_G = 8;      // rows per block in sl gin GEMM

// ---- intermediates as module-scope device globals (no d_ws dependence) ----
__device__ float g_P    [(size_t)2 * V * 512];   // 204.8 MB: emb@Wih^T + biases, per dir
__device__ float g_wl_h [(size_t)NW * W * 256];  // 98.3 MB
__device__ float g_sent [(size_t)NW * 256];      // 3.28 MB
__device__ float g_gin_f[(size_t)NW * 512];      // 6.55 MB
__device__ float g_gin_b[(size_t)NW * 512];      // 6.55 MB
__device__ float g_sl_h [(size_t)B * S * 256];   // 3.28 MB
__device__ float g_doc  [(size_t)B * 256];       // 64 KB

// ---- helpers ----
__device__ __forceinline__ float sigf(float x) { return 1.0f / (1.0f + __expf(-x)); }
// safe at +/-inf: x->-inf => exp->inf => -1; x->+inf => exp->0 => +1
__device__ __forceinline__ float tanh_fast(float x) { return 2.0f / (1.0f + __expf(-2.0f * x)) - 1.0f; }
__device__ __forceinline__ float dot4(float4 a, float4 b) {
    return fmaf(a.x, b.x, fmaf(a.y, b.y, fmaf(a.z, b.z, a.w * b.w)));
}

// ============================================================
// K0: vocab-level input projection: P[dir][v][512] = emb[v] @ Wih^T + bih + bhh.
// 50000 rows per dir, 8 rows/block -> 6250*2 = 12500 blocks, 256 threads.
// Latency hidden by TLP (48 blocks/CU worth of grid).
// ============================================================
__global__ __launch_bounds__(256) void k_emb_proj(
    const float* __restrict__ emb,
    const float* __restrict__ Wih_f, const float* __restrict__ bih_f, const float* __restrict__ bhh_f,
    const float* __restrict__ Wih_b, const float* __restrict__ bih_b, const float* __restrict__ bhh_b)
{
    const int dir = blockIdx.x & 1;
    const int r0  = (blockIdx.x >> 1) * 8;
    const float* Wih = dir ? Wih_b : Wih_f;
    const float* bih = dir ? bih_b : bih_f;
    const float* bhh = dir ? bhh_b : bhh_f;

    __shared__ float xs[8][E];   // 4 KB
    const int tid = threadIdx.x;
    {
        const int i = tid * 4;   // 1024 floats total, one float4/thread
        *(float4*)&(&xs[0][0])[i] = *(const float4*)&emb[(size_t)r0 * E + i];
    }
    __syncthreads();

    const int g0 = tid, g1 = tid + 256;
    const float* w0 = &Wih[(size_t)g0 * E];
    const float* w1 = &Wih[(size_t)g1 * E];
    float acc0[8], acc1[8];
    #pragma unroll
    for (int r = 0; r < 8; ++r) { acc0[r] = 0.f; acc1[r] = 0.f; }
    for (int k = 0; k < E; k += 4) {
        float4 wa = *(const float4*)(w0 + k);
        float4 wb = *(const float4*)(w1 + k);
        #pragma unroll
        for (int r = 0; r < 8; ++r) {
            float4 xv = *(const float4*)&xs[r][k];
            acc0[r] += dot4(wa, xv);
            acc1[r] += dot4(wb, xv);
        }
    }
    const float bv0 = bih[g0] + bhh[g0];
    const float bv1 = bih[g1] + bhh[g1];
    float* P = g_P + (size_t)dir * V * 512;
    #pragma unroll
    for (int r = 0; r < 8; ++r) {
        P[(size_t)(r0 + r) * 512 + g0] = acc0[r] + bv0;
        P[(size_t)(r0 + r) * 512 + g1] = acc1[r] + bv1;
    }
}

// ============================================================
// K1: word-level BiLSTM recurrence only: g = gather(P[id]) + h @ Whh^T.
// 1-D grid: blockIdx.x = sblk*2 + dir (1600 blocks), block 256.
// Double-buffered 16-k weight tiles for ILP latency hiding.
// LDS 12.5 KB. out: g_wl_h fp32 [NW][W][256], fwd [0:128) bwd [128:256).
// ============================================================
__global__ __launch_bounds__(256) void k_word_lstm(
    const int* __restrict__ ids,
    const float* __restrict__ Whh_f, const float* __restrict__ Whh_b)
{
    const int dir = blockIdx.x & 1;
    const int s0  = (blockIdx.x >> 1) * NSEQ_W;
    const float* Whh = dir ? Whh_b : Whh_f;
    const float* Pp  = g_P + (size_t)dir * V * 512;

    __shared__ float hs[NSEQ_W][H];      // 2 KB
    __shared__ float cs[NSEQ_W][H];      // 2 KB
    __shared__ float gs[NSEQ_W][G4];     // 8 KB
    __shared__ int   ids_sh[NSEQ_W * W]; // 480 B

    const int tid = threadIdx.x;
    if (tid < NSEQ_W * W) ids_sh[tid] = ids[s0 * W + tid];
    for (int i = tid; i < NSEQ_W * H; i += 256) { (&hs[0][0])[i] = 0.f; (&cs[0][0])[i] = 0.f; }
    const int g0 = tid, g1 = tid + 256;
    const float* w0p = &Whh[(size_t)g0 * H];
    const float* w1p = &Whh[(size_t)g1 * H];
    __syncthreads();

    for (int st = 0; st < W; ++st) {
        const int t = dir ? (W - 1 - st) : st;

        // issue P gathers first (waited only at gs-write; k-loop hides latency)
        float p0[NSEQ_W], p1[NSEQ_W];
        #pragma unroll
        for (int s = 0; s < NSEQ_W; ++s) {
            const float* Pr = Pp + (size_t)ids_sh[s * W + t] * 512;
            p0[s] = Pr[g0];
            p1[s] = Pr[g1];
        }

        // h @ Whh^T with double-buffered weight tiles (16 k per tile, 8 tiles)
        float acc0[NSEQ_W], acc1[NSEQ_W];
        #pragma unroll
        for (int s = 0; s < NSEQ_W; ++s) { acc0[s] = 0.f; acc1[s] = 0.f; }
        float4 wb0[2][4], wb1[2][4];
        #pragma unroll
        for (int c = 0; c < 4; ++c) {
            wb0[0][c] = *(const float4*)(w0p + c * 4);
            wb1[0][c] = *(const float4*)(w1p + c * 4);
        }
        #pragma unroll
        for (int tile = 0; tile < 8; ++tile) {
            const int cur = tile & 1, nxt = cur ^ 1;
            if (tile < 7) {
                #pragma unroll
                for (int c = 0; c < 4; ++c) {
                    wb0[nxt][c] = *(const float4*)(w0p + (tile + 1) * 16 + c * 4);
                    wb1[nxt][c] = *(const float4*)(w1p + (tile + 1) * 16 + c * 4);
                }
            }
            #pragma unroll
            for (int c = 0; c < 4; ++c) {
                const int k = tile * 16 + c * 4;
                #pragma unroll
                for (int s = 0; s < NSEQ_W; ++s) {
                    float4 hv = *(const float4*)&hs[s][k];
                    acc0[s] += dot4(wb0[cur][c], hv);
                    acc1[s] += dot4(wb1[cur][c], hv);
                }
            }
        }
        #pragma unroll
        for (int s = 0; s < NSEQ_W; ++s) {
            gs[s][g0] = acc0[s] + p0[s];
            gs[s][g1] = acc1[s] + p1[s];
        }
        __syncthreads();

        // gate update: 4 seqs x 128 cells = 512, 2 per thread
        #pragma unroll
        for (int r = 0; r < 2; ++r) {
            const int j = tid & 127;
            const int s = (tid >> 7) * 2 + r;
            float gi = gs[s][j], gf = gs[s][j + H], gg = gs[s][j + 2 * H], go = gs[s][j + 3 * H];
            float c = sigf(gf) * cs[s][j] + sigf(gi) * tanh_fast(gg);
            float h = sigf(go) * tanh_fast(c);
            cs[s][j] = c; hs[s][j] = h;
            g_wl_h[((size_t)(s0 + s) * W + t) * 256 + dir * H + j] = h;
        }
        __syncthreads();
    }
}

// ============================================================
// K2: word attention pool, CHUNKED (CH=10 -> 10 KB LDS), fp32 h.
// grid NW (1-D), block 128. Writes g_sent.
// ============================================================
template <int T, int CH>
__global__ __launch_bounds__(128) void k_attn_pool_word(
    const int* __restrict__ ids,
    const float* __restrict__ W1, const float* __restrict__ b1,
    const float* __restrict__ W2, const float* __restrict__ b2)
{
    const int n = blockIdx.x;
    __shared__ float hsh[CH][256];
    __shared__ float part[2][T];
    __shared__ float wsh[T];
    const int tid = threadIdx.x;
    const float* src = g_wl_h + (size_t)n * T * 256;
    const float b1v = b1[tid];
    const float w2v = W2[tid];
    const int wave = tid >> 6, lane = tid & 63;

    for (int c = 0; c < T; c += CH) {
        __syncthreads();
        for (int i = tid * 4; i < CH * 256; i += 512)
            *(float4*)&(&hsh[0][0])[i] = *(const float4*)&src[(size_t)c * 256 + i];
        __syncthreads();
        float acc[CH];
        #pragma unroll
        for (int u = 0; u < CH; ++u) acc[u] = 0.f;
        const float* w1p = &W1[tid * 256];
        for (int k = 0; k < 256; k += 4) {
            float4 w4 = *(const float4*)(w1p + k);
            #pragma unroll
            for (int u = 0; u < CH; ++u)
                acc[u] += dot4(w4, *(const float4*)&hsh[u][k]);
        }
        #pragma unroll
        for (int u = 0; u < CH; ++u) {
            float v = w2v * tanh_fast(acc[u] + b1v);
            #pragma unroll
            for (int off = 32; off > 0; off >>= 1) v += __shfl_down(v, off, 64);
            if (lane == 0) part[wave][c + u] = v;
        }
    }
    __syncthreads();

    if (tid < T) {
        bool valid = (ids[n * T + tid] != 0);
        wsh[tid] = valid ? (part[0][tid] + part[1][tid] + b2[0]) : -INFINITY;
    }
    __syncthreads();
    if (tid == 0) {
        float m = -INFINITY;
        for (int t = 0; t < T; ++t) m = fmaxf(m, wsh[t]);
        float sum = 0.f;
        for (int t = 0; t < T; ++t) sum += (wsh[t] == -INFINITY) ? 0.f : __expf(wsh[t] - m);
        const float inv = (sum > 0.f) ? 1.f / sum : 0.f;
        for (int t = 0; t < T; ++t) wsh[t] = (wsh[t] == -INFINITY) ? 0.f : __expf(wsh[t] - m) * inv;
    }

    float o0 = 0.f, o1 = 0.f;
    for (int c = 0; c < T; c += CH) {
        __syncthreads();
        for (int i = tid * 4; i < CH * 256; i += 512)
            *(float4*)&(&hsh[0][0])[i] = *(const float4*)&src[(size_t)c * 256 + i];
        __syncthreads();
        #pragma unroll
        for (int u = 0; u < CH; ++u) {
            float w = wsh[c + u];
            o0 += w * hsh[u][tid];
            o1 += w * hsh[u][tid + 128];
        }
    }
    g_sent[(size_t)n * 256 + tid] = o0;
    g_sent[(size_t)n * 256 + tid + 128] = o1;
}

// ============================================================
// K3: sentence LSTM input projection: gin = sent @ Wih^T + bih + bhh
// 1-D grid: blockIdx.x = rblk*2 + dir (800 blocks), block 256.
// ============================================================
__global__ __launch_bounds__(256) void k_sl_gin(
    const float* __restrict__ Wih_f, const float* __restrict__ bih_f, const float* __restrict__ bhh_f,
    const float* __restrict__ Wih_b, const float* __restrict__ bih_b, const float* __restrict__ bhh_b)
{
    const int dir = blockIdx.x & 1;
    const float* Wih = dir ? Wih_b : Wih_f;
    const float* bih = dir ? bih_b : bih_f;
    const float* bhh = dir ? bhh_b : bhh_f;
    float* gin = dir ? g_gin_b : g_gin_f;
    const int r0 = (blockIdx.x >> 1) * NSEQ_G;

    __shared__ float xs[NSEQ_G][256];
    const int tid = threadIdx.x;
    for (int i = tid * 4; i < NSEQ_G * 256; i += 1024)
        *(float4*)&(&xs[0][0])[i] = *(const float4*)&g_sent[(size_t)r0 * 256 + i];
    __syncthreads();

    const int g0 = tid, g1 = tid + 256;
    float acc0[NSEQ_G], acc1[NSEQ_G];
    #pragma unroll
    for (int s = 0; s < NSEQ_G; ++s) { acc0[s] = 0.f; acc1[s] = 0.f; }
    const float* w0 = &Wih[g0 * 256]; const float* w1 = &Wih[g1 * 256];
    for (int k = 0; k < 256; k += 4) {
        float4 wa = *(const float4*)(w0 + k);
        float4 wb = *(const float4*)(w1 + k);
        #pragma unroll
        for (int s = 0; s < NSEQ_G; ++s) {
            float4 xv = *(const float4*)&xs[s][k];
            acc0[s] += dot4(wa, xv);
            acc1[s] += dot4(wb, xv);
        }
    }
    const float bv0 = bih[g0] + bhh[g0];
    const float bv1 = bih[g1] + bhh[g1];
    #pragma unroll
    for (int s = 0; s < NSEQ_G; ++s) {
        gin[(size_t)(r0 + s) * 512 + g0] = acc0[s] + bv0;
        gin[(size_t)(r0 + s) * 512 + g1] = acc1[s] + bv1;
    }
}

// ============================================================
// K4: sentence BiLSTM, persistent over T=50.
// 1-D grid: blockIdx.x = bblk*2 + dir (32 blocks), block 256. LDS 12 KB.
// ============================================================
__global__ __launch_bounds__(256) void k_sent_lstm(
    const float* __restrict__ Whh_f, const float* __restrict__ Whh_b)
{
    const int dir = blockIdx.x & 1;
    const float* gin = dir ? g_gin_b : g_gin_f;
    const float* Whh = dir ? Whh_b : Whh_f;
    const int b0 = (blockIdx.x >> 1) * NSEQ_S;

    __shared__ float hs[NSEQ_S][H];
    __shared__ float cs[NSEQ_S][H];
    __shared__ float gs[NSEQ_S][G4];
    const int tid = threadIdx.x;
    for (int i = tid; i < NSEQ_S * H; i += 256) { (&hs[0][0])[i] = 0.f; (&cs[0][0])[i] = 0.f; }
    const int g0 = tid, g1 = tid + 256;
    const float* w0 = &Whh[g0 * H]; const float* w1 = &Whh[g1 * H];
    __syncthreads();

    for (int st = 0; st < S; ++st) {
        const int t = dir ? (S - 1 - st) : st;
        float acc0[NSEQ_S], acc1[NSEQ_S];
        #pragma unroll
        for (int s = 0; s < NSEQ_S; ++s) {
            acc0[s] = gin[(size_t)((b0 + s) * S + t) * 512 + g0];
            acc1[s] = gin[(size_t)((b0 + s) * S + t) * 512 + g1];
        }
        for (int k = 0; k < H; k += 4) {
            float4 va = *(const float4*)(w0 + k);
            float4 vb = *(const float4*)(w1 + k);
            #pragma unroll
            for (int s = 0; s < NSEQ_S; ++s) {
                float4 hv = *(const float4*)&hs[s][k];
                acc0[s] += dot4(va, hv);
                acc1[s] += dot4(vb, hv);
            }
        }
        #pragma unroll
        for (int s = 0; s < NSEQ_S; ++s) { gs[s][g0] = acc0[s]; gs[s][g1] = acc1[s]; }
        __syncthreads();
        #pragma unroll
        for (int r = 0; r < 2; ++r) {
            const int j = tid & 127;
            const int s = (tid >> 7) * 2 + r;
            float gi = gs[s][j], gf = gs[s][j + H], gg = gs[s][j + 2 * H], go = gs[s][j + 3 * H];
            float c = sigf(gf) * cs[s][j] + sigf(gi) * tanh_fast(gg);
            float h = sigf(go) * tanh_fast(c);
            cs[s][j] = c; hs[s][j] = h;
            g_sl_h[(size_t)((b0 + s) * S + t) * 256 + dir * H + j] = h;
        }
        __syncthreads();
    }
}

// ============================================================
// K5: document attention pool, CHUNKED (10 KB LDS), fp32 input.
// grid B (1-D), block 128. Writes g_doc.
// ============================================================
template <int T, int CH>
__global__ __launch_bounds__(128) void k_attn_pool_doc(
    const int* __restrict__ ids,
    const float* __restrict__ W1, const float* __restrict__ b1,
    const float* __restrict__ W2, const float* __restrict__ b2)
{
    const int n = blockIdx.x;
    __shared__ float hsh[CH][256];
    __shared__ float part[2][T];
    __shared__ float wsh[T];
    const int tid = threadIdx.x;
    const float* src = g_sl_h + (size_t)n * T * 256;
    const float b1v = b1[tid];
    const float w2v = W2[tid];
    const int wave = tid >> 6, lane = tid & 63;

    for (int c = 0; c < T; c += CH) {
        __syncthreads();
        for (int i = tid * 4; i < CH * 256; i += 512)
            *(float4*)&(&hsh[0][0])[i] = *(const float4*)&src[(size_t)c * 256 + i];
        __syncthreads();
        float acc[CH];
        #pragma unroll
        for (int u = 0; u < CH; ++u) acc[u] = 0.f;
        const float* w1p = &W1[tid * 256];
        for (int k = 0; k < 256; k += 4) {
            float4 w4 = *(const float4*)(w1p + k);
            #pragma unroll
            for (int u = 0; u < CH; ++u)
                acc[u] += dot4(w4, *(const float4*)&hsh[u][k]);
        }
        #pragma unroll
        for (int u = 0; u < CH; ++u) {
            float v = w2v * tanh_fast(acc[u] + b1v);
            #pragma unroll
            for (int off = 32; off > 0; off >>= 1) v += __shfl_down(v, off, 64);
            if (lane == 0) part[wave][c + u] = v;
        }
    }
    __syncthreads();

    if (tid < T) {
        bool valid = false;
        const int* ip = &ids[((size_t)n * T + tid) * W];
        for (int w = 0; w < W; ++w) valid |= (ip[w] != 0);
        wsh[tid] = valid ? (part[0][tid] + part[1][tid] + b2[0]) : -INFINITY;
    }
    __syncthreads();
    if (tid == 0) {
        float m = -INFINITY;
        for (int t = 0; t < T; ++t) m = fmaxf(m, wsh[t]);
        float sum = 0.f;
        for (int t = 0; t < T; ++t) sum += (wsh[t] == -INFINITY) ? 0.f : __expf(wsh[t] - m);
        const float inv = (sum > 0.f) ? 1.f / sum : 0.f;
        for (int t = 0; t < T; ++t) wsh[t] = (wsh[t] == -INFINITY) ? 0.f : __expf(wsh[t] - m) * inv;
    }

    float o0 = 0.f, o1 = 0.f;
    for (int c = 0; c < T; c += CH) {
        __syncthreads();
        for (int i = tid * 4; i < CH * 256; i += 512)
            *(float4*)&(&hsh[0][0])[i] = *(const float4*)&src[(size_t)c * 256 + i];
        __syncthreads();
        #pragma unroll
        for (int u = 0; u < CH; ++u) {
            float w = wsh[c + u];
            o0 += w * hsh[u][tid];
            o1 += w * hsh[u][tid + 128];
        }
    }
    g_doc[(size_t)n * 256 + tid] = o0;
    g_doc[(size_t)n * 256 + tid + 128] = o1;
}

// ============================================================
// K6: classifier. Output fp32 (reference returns float32 logits).
// grid B, block 128.
// ============================================================
__global__ __launch_bounds__(128) void k_classifier(
    const float* __restrict__ W1, const float* __restrict__ b1,
    const float* __restrict__ W2, const float* __restrict__ b2,
    float* __restrict__ out /* [B][3] fp32 */)
{
    const int b = blockIdx.x;
    __shared__ float dsh[256];
    __shared__ float hsh[128];
    const int tid = threadIdx.x;
    if (tid < 64) *(float4*)&dsh[tid * 4] = *(const float4*)&g_doc[(size_t)b * 256 + tid * 4];
    __syncthreads();
    float acc = 0.f;
    const float* w1p = &W1[tid * 256];
    for (int k = 0; k < 256; k += 4) {
        float4 w4 = *(const float4*)(w1p + k);
        float4 d4 = *(const float4*)&dsh[k];
        acc += dot4(w4, d4);
    }
    hsh[tid] = fmaxf(acc + b1[tid], 0.f);
    __syncthreads();
    if (tid < 3) {
        float a = b2[tid];
        const float* w2p = &W2[tid * 128];
        for (int j = 0; j < 128; ++j) a += w2p[j] * hsh[j];
        out[b * 3 + tid] = a;
    }
}

// ============================================================
extern "C" void kernel_launch(void* const* d_in, const int* in_sizes, int n_in,
                              void* d_out, int out_size, void* d_ws, size_t ws_size,
                              hipStream_t stream) {
    // Inputs fp32, ids int32, OUTPUT fp32. d_ws unused.
    const int*   ids      = (const int*)d_in[0];
    const float* emb      = (const float*)d_in[1];
    const float* wl_Wih_f = (const float*)d_in[2];
    const float* wl_Whh_f = (const float*)d_in[3];
    const float* wl_bih_f = (const float*)d_in[4];
    const float* wl_bhh_f = (const float*)d_in[5];
    const float* wl_Wih_b = (const float*)d_in[6];
    const float* wl_Whh_b = (const float*)d_in[7];
    const float* wl_bih_b = (const float*)d_in[8];
    const float* wl_bhh_b = (const float*)d_in[9];
    const float* sl_Wih_f = (const float*)d_in[10];
    const float* sl_Whh_f = (const float*)d_in[11];
    const float* sl_bih_f = (const float*)d_in[12];
    const float* sl_bhh_f = (const float*)d_in[13];
    const float* sl_Wih_b = (const float*)d_in[14];
    const float* sl_Whh_b = (const float*)d_in[15];
    const float* sl_bih_b = (const float*)d_in[16];
    const float* sl_bhh_b = (const float*)d_in[17];
    const float* wa_W1 = (const float*)d_in[18];
    const float* wa_b1 = (const float*)d_in[19];
    const float* wa_W2 = (const float*)d_in[20];
    const float* wa_b2 = (const float*)d_in[21];
    const float* sa_W1 = (const float*)d_in[22];
    const float* sa_b1 = (const float*)d_in[23];
    const float* sa_W2 = (const float*)d_in[24];
    const float* sa_b2 = (const float*)d_in[25];
    const float* cl_W1 = (const float*)d_in[26];
    const float* cl_b1 = (const float*)d_in[27];
    const float* cl_W2 = (const float*)d_in[28];
    const float* cl_b2 = (const float*)d_in[29];

    k_emb_proj<<<(V / 8) * 2, 256, 0, stream>>>(
        emb, wl_Wih_f, wl_bih_f, wl_bhh_f, wl_Wih_b, wl_bih_b, wl_bhh_b);

    k_word_lstm<<<NW / NSEQ_W * 2, 256, 0, stream>>>(ids, wl_Whh_f, wl_Whh_b);

    k_attn_pool_word<W, 10><<<NW, 128, 0, stream>>>(ids, wa_W1, wa_b1, wa_W2, wa_b2);

    k_sl_gin<<<NW / NSEQ_G * 2, 256, 0, stream>>>(
        sl_Wih_f, sl_bih_f, sl_bhh_f, sl_Wih_b, sl_bih_b, sl_bhh_b);

    k_sent_lstm<<<B / NSEQ_S * 2, 256, 0, stream>>>(sl_Whh_f, sl_Whh_b);

    k_attn_pool_doc<S, 10><<<B, 128, 0, stream>>>(ids, sa_W1, sa_b1, sa_W2, sa_b2);

    k_classifier<<<B, 128, 0, stream>>>(cl_W1, cl_b1, cl_W2, cl_b2, (float*)d_out);
}

// Round 8
// 2500.414 us; speedup vs baseline: 1.6158x; 1.0801x over previous
//
#include <hip/hip_runtime.h>
#include <math.h>

// ---- dims ----
constexpr int B  = 64;
constexpr int S  = 50;
constexpr int W  = 30;
constexpr int E  = 128;
constexpr int H  = 128;
constexpr int NW = B * S;      // 3200 word sequences
constexpr int V  = 50000;      // vocab
constexpr int NSEQ_W = 16;     // word seqs per block
constexpr int NSEQ_G = 8;      // rows per block in sl gin GEMM

// ---- intermediates as module-scope device globals ----
__device__ float g_P    [(size_t)2 * V * 512];   // 204.8 MB: emb@Wih^T + biases, per dir
__device__ float g_wl_h [(size_t)NW * W * 256];  // 98.3 MB
__device__ float g_sent [(size_t)NW * 256];      // 3.28 MB
__device__ float g_gin_f[(size_t)NW * 512];      // 6.55 MB
__device__ float g_gin_b[(size_t)NW * 512];      // 6.55 MB
__device__ float g_sl_h [(size_t)B * S * 256];   // 3.28 MB
__device__ float g_doc  [(size_t)B * 256];       // 64 KB

// ---- helpers ----
__device__ __forceinline__ float sigf(float x) { return 1.0f / (1.0f + __expf(-x)); }
__device__ __forceinline__ float tanh_fast(float x) { return 2.0f / (1.0f + __expf(-2.0f * x)) - 1.0f; }
__device__ __forceinline__ float dot4(float4 a, float4 b) {
    return fmaf(a.x, b.x, fmaf(a.y, b.y, fmaf(a.z, b.z, a.w * b.w)));
}

// ============================================================
// K0: vocab-level input projection: P[dir][v][512] = emb[v]@Wih^T + bih + bhh.
// (unchanged from R7 — not the bottleneck per counters)
// ============================================================
__global__ __launch_bounds__(256) void k_emb_proj(
    const float* __restrict__ emb,
    const float* __restrict__ Wih_f, const float* __restrict__ bih_f, const float* __restrict__ bhh_f,
    const float* __restrict__ Wih_b, const float* __restrict__ bih_b, const float* __restrict__ bhh_b)
{
    const int dir = blockIdx.x & 1;
    const int r0  = (blockIdx.x >> 1) * 8;
    const float* Wih = dir ? Wih_b : Wih_f;
    const float* bih = dir ? bih_b : bih_f;
    const float* bhh = dir ? bhh_b : bhh_f;

    __shared__ float xs[8][E];
    const int tid = threadIdx.x;
    {
        const int i = tid * 4;
        *(float4*)&(&xs[0][0])[i] = *(const float4*)&emb[(size_t)r0 * E + i];
    }
    __syncthreads();

    const int g0 = tid, g1 = tid + 256;
    const float* w0 = &Wih[(size_t)g0 * E];
    const float* w1 = &Wih[(size_t)g1 * E];
    float acc0[8], acc1[8];
    #pragma unroll
    for (int r = 0; r < 8; ++r) { acc0[r] = 0.f; acc1[r] = 0.f; }
    for (int k = 0; k < E; k += 4) {
        float4 wa = *(const float4*)(w0 + k);
        float4 wb = *(const float4*)(w1 + k);
        #pragma unroll
        for (int r = 0; r < 8; ++r) {
            float4 xv = *(const float4*)&xs[r][k];
            acc0[r] += dot4(wa, xv);
            acc1[r] += dot4(wb, xv);
        }
    }
    const float bv0 = bih[g0] + bhh[g0];
    const float bv1 = bih[g1] + bhh[g1];
    float* P = g_P + (size_t)dir * V * 512;
    #pragma unroll
    for (int r = 0; r < 8; ++r) {
        P[(size_t)(r0 + r) * 512 + g0] = acc0[r] + bv0;
        P[(size_t)(r0 + r) * 512 + g1] = acc1[r] + bv1;
    }
}

// ============================================================
// K1: word BiLSTM recurrence. Thread j owns ALL 4 gates of cell j
// -> cell update in-thread, c-state in regs, ONE barrier/step.
// 256 thr: grp=tid>>7 handles 8 of the block's 16 seqs.
// grid = (3200/16)*2 = 400 blocks. LDS 18.3 KB.
// ============================================================
__global__ __launch_bounds__(256) void k_word_lstm(
    const int* __restrict__ ids,
    const float* __restrict__ Whh_f, const float* __restrict__ Whh_b)
{
    const int dir = blockIdx.x & 1;
    const int s0  = (blockIdx.x >> 1) * NSEQ_W;
    const float* Whh = dir ? Whh_b : Whh_f;
    const float* Pp  = g_P + (size_t)dir * V * 512;

    __shared__ float hs[2][NSEQ_W][H];   // 16 KB, double-buffered
    __shared__ int   ids_sh[NSEQ_W * W]; // 1.9 KB

    const int tid = threadIdx.x;
    const int j   = tid & 127;   // cell index
    const int sb  = (tid >> 7) * 8;

    for (int i = tid; i < NSEQ_W * W; i += 256) ids_sh[i] = ids[s0 * W + i];
    for (int i = tid; i < 2 * NSEQ_W * H; i += 256) (&hs[0][0][0])[i] = 0.f;

    const float* wr0 = Whh + (size_t)(j      ) * H;
    const float* wr1 = Whh + (size_t)(j + 128) * H;
    const float* wr2 = Whh + (size_t)(j + 256) * H;
    const float* wr3 = Whh + (size_t)(j + 384) * H;

    float cst[8];
    #pragma unroll
    for (int s = 0; s < 8; ++s) cst[s] = 0.f;

    __syncthreads();

    int cur = 0;
    for (int st = 0; st < W; ++st) {
        const int t = dir ? (W - 1 - st) : st;

        // prefetch P (gate pre-activations incl. biases) for this step
        float pg0[8], pg1[8], pg2[8], pg3[8];
        #pragma unroll
        for (int s = 0; s < 8; ++s) {
            const float* Pr = Pp + (size_t)ids_sh[(sb + s) * W + t] * 512;
            pg0[s] = Pr[j];
            pg1[s] = Pr[j + 128];
            pg2[s] = Pr[j + 256];
            pg3[s] = Pr[j + 384];
        }

        float a0[8], a1[8], a2[8], a3[8];
        #pragma unroll
        for (int s = 0; s < 8; ++s) { a0[s] = 0.f; a1[s] = 0.f; a2[s] = 0.f; a3[s] = 0.f; }

        for (int k = 0; k < H; k += 4) {
            float4 w0 = *(const float4*)(wr0 + k);
            float4 w1 = *(const float4*)(wr1 + k);
            float4 w2 = *(const float4*)(wr2 + k);
            float4 w3 = *(const float4*)(wr3 + k);
            #pragma unroll
            for (int s = 0; s < 8; ++s) {
                float4 hv = *(const float4*)&hs[cur][sb + s][k];  // wave-uniform addr: LDS broadcast
                a0[s] += dot4(w0, hv);
                a1[s] += dot4(w1, hv);
                a2[s] += dot4(w2, hv);
                a3[s] += dot4(w3, hv);
            }
        }

        #pragma unroll
        for (int s = 0; s < 8; ++s) {
            float gi = a0[s] + pg0[s];
            float gf = a1[s] + pg1[s];
            float gg = a2[s] + pg2[s];
            float go = a3[s] + pg3[s];
            float c = sigf(gf) * cst[s] + sigf(gi) * tanh_fast(gg);
            float h = sigf(go) * tanh_fast(c);
            cst[s] = c;
            hs[cur ^ 1][sb + s][j] = h;
            g_wl_h[((size_t)(s0 + sb + s) * W + t) * 256 + dir * H + j] = h;
        }
        __syncthreads();
        cur ^= 1;
    }
}

// ============================================================
// K2: word attention pool, SINGLE-PASS (T=30 -> 30.7 KB LDS fits).
// 128 thr: lane handles W1 rows {lane, lane+64}; wave wv handles t-half.
// grid NW.
// ============================================================
template <int T>
__global__ __launch_bounds__(128) void k_attn_pool_word(
    const int* __restrict__ ids,
    const float* __restrict__ W1, const float* __restrict__ b1,
    const float* __restrict__ W2, const float* __restrict__ b2)
{
    constexpr int TH = T / 2;
    const int n = blockIdx.x;
    __shared__ float hsh[T][256];   // 30.7 KB
    __shared__ float wsh[T];
    const int tid = threadIdx.x;
    const int lane = tid & 63;
    const int wv   = tid >> 6;

    const float* src = g_wl_h + (size_t)n * T * 256;
    for (int i = tid * 4; i < T * 256; i += 512)
        *(float4*)&(&hsh[0][0])[i] = *(const float4*)&src[i];
    __syncthreads();

    const int j0 = lane, j1 = lane + 64;
    const int tbase = wv * TH;
    float acc0[TH], acc1[TH];
    #pragma unroll
    for (int u = 0; u < TH; ++u) { acc0[u] = 0.f; acc1[u] = 0.f; }
    const float* w1a = &W1[j0 * 256];
    const float* w1b = &W1[j1 * 256];
    for (int k = 0; k < 256; k += 4) {
        float4 wa = *(const float4*)(w1a + k);
        float4 wb = *(const float4*)(w1b + k);
        #pragma unroll
        for (int u = 0; u < TH; ++u) {
            float4 hv = *(const float4*)&hsh[tbase + u][k];
            acc0[u] += dot4(wa, hv);
            acc1[u] += dot4(wb, hv);
        }
    }
    const float b1a = b1[j0], b1b = b1[j1];
    const float w2a = W2[j0], w2b = W2[j1];
    #pragma unroll
    for (int u = 0; u < TH; ++u) {
        float v = w2a * tanh_fast(acc0[u] + b1a) + w2b * tanh_fast(acc1[u] + b1b);
        #pragma unroll
        for (int off = 32; off > 0; off >>= 1) v += __shfl_down(v, off, 64);
        if (lane == 0) wsh[tbase + u] = v;
    }
    __syncthreads();

    // mask (parallel) then softmax (thread 0)
    if (tid < T) {
        bool valid = (ids[n * T + tid] != 0);
        wsh[tid] = valid ? (wsh[tid] + b2[0]) : -INFINITY;
    }
    __syncthreads();
    if (tid == 0) {
        float m = -INFINITY;
        for (int t = 0; t < T; ++t) m = fmaxf(m, wsh[t]);
        float sum = 0.f;
        for (int t = 0; t < T; ++t) sum += (wsh[t] == -INFINITY) ? 0.f : __expf(wsh[t] - m);
        const float inv = (sum > 0.f) ? 1.f / sum : 0.f;
        for (int t = 0; t < T; ++t) wsh[t] = (wsh[t] == -INFINITY) ? 0.f : __expf(wsh[t] - m) * inv;
    }
    __syncthreads();

    float o0 = 0.f, o1 = 0.f;
    #pragma unroll
    for (int t = 0; t < T; ++t) {
        float w = wsh[t];
        o0 += w * hsh[t][tid];
        o1 += w * hsh[t][tid + 128];
    }
    g_sent[(size_t)n * 256 + tid] = o0;
    g_sent[(size_t)n * 256 + tid + 128] = o1;
}

// ============================================================
// K3: sentence LSTM input projection (unchanged from R7).
// ============================================================
__global__ __launch_bounds__(256) void k_sl_gin(
    const float* __restrict__ Wih_f, const float* __restrict__ bih_f, const float* __restrict__ bhh_f,
    const float* __restrict__ Wih_b, const float* __restrict__ bih_b, const float* __restrict__ bhh_b)
{
    const int dir = blockIdx.x & 1;
    const float* Wih = dir ? Wih_b : Wih_f;
    const float* bih = dir ? bih_b : bih_f;
    const float* bhh = dir ? bhh_b : bhh_f;
    float* gin = dir ? g_gin_b : g_gin_f;
    const int r0 = (blockIdx.x >> 1) * NSEQ_G;

    __shared__ float xs[NSEQ_G][256];
    const int tid = threadIdx.x;
    for (int i = tid * 4; i < NSEQ_G * 256; i += 1024)
        *(float4*)&(&xs[0][0])[i] = *(const float4*)&g_sent[(size_t)r0 * 256 + i];
    __syncthreads();

    const int g0 = tid, g1 = tid + 256;
    float acc0[NSEQ_G], acc1[NSEQ_G];
    #pragma unroll
    for (int s = 0; s < NSEQ_G; ++s) { acc0[s] = 0.f; acc1[s] = 0.f; }
    const float* w0 = &Wih[g0 * 256]; const float* w1 = &Wih[g1 * 256];
    for (int k = 0; k < 256; k += 4) {
        float4 wa = *(const float4*)(w0 + k);
        float4 wb = *(const float4*)(w1 + k);
        #pragma unroll
        for (int s = 0; s < NSEQ_G; ++s) {
            float4 xv = *(const float4*)&xs[s][k];
            acc0[s] += dot4(wa, xv);
            acc1[s] += dot4(wb, xv);
        }
    }
    const float bv0 = bih[g0] + bhh[g0];
    const float bv1 = bih[g1] + bhh[g1];
    #pragma unroll
    for (int s = 0; s < NSEQ_G; ++s) {
        gin[(size_t)(r0 + s) * 512 + g0] = acc0[s] + bv0;
        gin[(size_t)(r0 + s) * 512 + g1] = acc1[s] + bv1;
    }
}

// ============================================================
// K4: sentence BiLSTM. Thread j owns cell j's 4 gates, 1 seq/block.
// grid = B*2 = 128 blocks, 128 threads. 1 barrier/step. LDS 1 KB.
// ============================================================
__global__ __launch_bounds__(128) void k_sent_lstm(
    const float* __restrict__ Whh_f, const float* __restrict__ Whh_b)
{
    const int dir = blockIdx.x & 1;
    const int b   = blockIdx.x >> 1;
    const float* Whh = dir ? Whh_b : Whh_f;
    const float* gin = dir ? g_gin_b : g_gin_f;

    __shared__ float hs[2][H];
    const int j = threadIdx.x;
    const float* wr0 = Whh + (size_t)(j      ) * H;
    const float* wr1 = Whh + (size_t)(j + 128) * H;
    const float* wr2 = Whh + (size_t)(j + 256) * H;
    const float* wr3 = Whh + (size_t)(j + 384) * H;

    hs[0][j] = 0.f;
    float cst = 0.f;
    __syncthreads();

    int cur = 0;
    for (int st = 0; st < S; ++st) {
        const int t = dir ? (S - 1 - st) : st;
        const float* gp = gin + (size_t)(b * S + t) * 512;
        float p0 = gp[j], p1 = gp[j + 128], p2 = gp[j + 256], p3 = gp[j + 384];

        float a0 = 0.f, a1 = 0.f, a2 = 0.f, a3 = 0.f;
        for (int k = 0; k < H; k += 4) {
            float4 hv = *(const float4*)&hs[cur][k];
            a0 += dot4(*(const float4*)(wr0 + k), hv);
            a1 += dot4(*(const float4*)(wr1 + k), hv);
            a2 += dot4(*(const float4*)(wr2 + k), hv);
            a3 += dot4(*(const float4*)(wr3 + k), hv);
        }
        float c = sigf(a1 + p1) * cst + sigf(a0 + p0) * tanh_fast(a2 + p2);
        float h = sigf(a3 + p3) * tanh_fast(c);
        cst = c;
        hs[cur ^ 1][j] = h;
        g_sl_h[(size_t)(b * S + t) * 256 + dir * H + j] = h;
        __syncthreads();
        cur ^= 1;
    }
}

// ============================================================
// K5: document attention pool, SINGLE-PASS (T=50 -> 51.2 KB LDS).
// grid B, 128 threads. Same structure as K2; mask scans W ids.
// ============================================================
template <int T>
__global__ __launch_bounds__(128) void k_attn_pool_doc(
    const int* __restrict__ ids,
    const float* __restrict__ W1, const float* __restrict__ b1,
    const float* __restrict__ W2, const float* __restrict__ b2)
{
    constexpr int TH = T / 2;
    const int n = blockIdx.x;
    __shared__ float hsh[T][256];   // 51.2 KB
    __shared__ float wsh[T];
    const int tid = threadIdx.x;
    const int lane = tid & 63;
    const int wv   = tid >> 6;

    const float* src = g_sl_h + (size_t)n * T * 256;
    for (int i = tid * 4; i < T * 256; i += 512)
        *(float4*)&(&hsh[0][0])[i] = *(const float4*)&src[i];
    __syncthreads();

    const int j0 = lane, j1 = lane + 64;
    const int tbase = wv * TH;
    float acc0[TH], acc1[TH];
    #pragma unroll
    for (int u = 0; u < TH; ++u) { acc0[u] = 0.f; acc1[u] = 0.f; }
    const float* w1a = &W1[j0 * 256];
    const float* w1b = &W1[j1 * 256];
    for (int k = 0; k < 256; k += 4) {
        float4 wa = *(const float4*)(w1a + k);
        float4 wb = *(const float4*)(w1b + k);
        #pragma unroll
        for (int u = 0; u < TH; ++u) {
            float4 hv = *(const float4*)&hsh[tbase + u][k];
            acc0[u] += dot4(wa, hv);
            acc1[u] += dot4(wb, hv);
        }
    }
    const float b1a = b1[j0], b1b = b1[j1];
    const float w2a = W2[j0], w2b = W2[j1];
    #pragma unroll
    for (int u = 0; u < TH; ++u) {
        float v = w2a * tanh_fast(acc0[u] + b1a) + w2b * tanh_fast(acc1[u] + b1b);
        #pragma unroll
        for (int off = 32; off > 0; off >>= 1) v += __shfl_down(v, off, 64);
        if (lane == 0) wsh[tbase + u] = v;
    }
    __syncthreads();

    if (tid < T) {
        bool valid = false;
        const int* ip = &ids[((size_t)n * T + tid) * W];
        for (int w = 0; w < W; ++w) valid |= (ip[w] != 0);
        wsh[tid] = valid ? (wsh[tid] + b2[0]) : -INFINITY;
    }
    __syncthreads();
    if (tid == 0) {
        float m = -INFINITY;
        for (int t = 0; t < T; ++t) m = fmaxf(m, wsh[t]);
        float sum = 0.f;
        for (int t = 0; t < T; ++t) sum += (wsh[t] == -INFINITY) ? 0.f : __expf(wsh[t] - m);
        const float inv = (sum > 0.f) ? 1.f / sum : 0.f;
        for (int t = 0; t < T; ++t) wsh[t] = (wsh[t] == -INFINITY) ? 0.f : __expf(wsh[t] - m) * inv;
    }
    __syncthreads();

    float o0 = 0.f, o1 = 0.f;
    #pragma unroll
    for (int t = 0; t < T; ++t) {
        float w = wsh[t];
        o0 += w * hsh[t][tid];
        o1 += w * hsh[t][tid + 128];
    }
    g_doc[(size_t)n * 256 + tid] = o0;
    g_doc[(size_t)n * 256 + tid + 128] = o1;
}

// ============================================================
// K6: classifier (fp32 out).
// ============================================================
__global__ __launch_bounds__(128) void k_classifier(
    const float* __restrict__ W1, const float* __restrict__ b1,
    const float* __restrict__ W2, const float* __restrict__ b2,
    float* __restrict__ out)
{
    const int b = blockIdx.x;
    __shared__ float dsh[256];
    __shared__ float hsh[128];
    const int tid = threadIdx.x;
    if (tid < 64) *(float4*)&dsh[tid * 4] = *(const float4*)&g_doc[(size_t)b * 256 + tid * 4];
    __syncthreads();
    float acc = 0.f;
    const float* w1p = &W1[tid * 256];
    for (int k = 0; k < 256; k += 4) {
        float4 w4 = *(const float4*)(w1p + k);
        float4 d4 = *(const float4*)&dsh[k];
        acc += dot4(w4, d4);
    }
    hsh[tid] = fmaxf(acc + b1[tid], 0.f);
    __syncthreads();
    if (tid < 3) {
        float a = b2[tid];
        const float* w2p = &W2[tid * 128];
        for (int j = 0; j < 128; ++j) a += w2p[j] * hsh[j];
        out[b * 3 + tid] = a;
    }
}

// ============================================================
extern "C" void kernel_launch(void* const* d_in, const int* in_sizes, int n_in,
                              void* d_out, int out_size, void* d_ws, size_t ws_size,
                              hipStream_t stream) {
    const int*   ids      = (const int*)d_in[0];
    const float* emb      = (const float*)d_in[1];
    const float* wl_Wih_f = (const float*)d_in[2];
    const float* wl_Whh_f = (const float*)d_in[3];
    const float* wl_bih_f = (const float*)d_in[4];
    const float* wl_bhh_f = (const float*)d_in[5];
    const float* wl_Wih_b = (const float*)d_in[6];
    const float* wl_Whh_b = (const float*)d_in[7];
    const float* wl_bih_b = (const float*)d_in[8];
    const float* wl_bhh_b = (const float*)d_in[9];
    const float* sl_Wih_f = (const float*)d_in[10];
    const float* sl_Whh_f = (const float*)d_in[11];
    const float* sl_bih_f = (const float*)d_in[12];
    const float* sl_bhh_f = (const float*)d_in[13];
    const float* sl_Wih_b = (const float*)d_in[14];
    const float* sl_Whh_b = (const float*)d_in[15];
    const float* sl_bih_b = (const float*)d_in[16];
    const float* sl_bhh_b = (const float*)d_in[17];
    const float* wa_W1 = (const float*)d_in[18];
    const float* wa_b1 = (const float*)d_in[19];
    const float* wa_W2 = (const float*)d_in[20];
    const float* wa_b2 = (const float*)d_in[21];
    const float* sa_W1 = (const float*)d_in[22];
    const float* sa_b1 = (const float*)d_in[23];
    const float* sa_W2 = (const float*)d_in[24];
    const float* sa_b2 = (const float*)d_in[25];
    const float* cl_W1 = (const float*)d_in[26];
    const float* cl_b1 = (const float*)d_in[27];
    const float* cl_W2 = (const float*)d_in[28];
    const float* cl_b2 = (const float*)d_in[29];

    k_emb_proj<<<(V / 8) * 2, 256, 0, stream>>>(
        emb, wl_Wih_f, wl_bih_f, wl_bhh_f, wl_Wih_b, wl_bih_b, wl_bhh_b);

    k_word_lstm<<<NW / NSEQ_W * 2, 256, 0, stream>>>(ids, wl_Whh_f, wl_Whh_b);

    k_attn_pool_word<W><<<NW, 128, 0, stream>>>(ids, wa_W1, wa_b1, wa_W2, wa_b2);

    k_sl_gin<<<NW / NSEQ_G * 2, 256, 0, stream>>>(
        sl_Wih_f, sl_bih_f, sl_bhh_f, sl_Wih_b, sl_bih_b, sl_bhh_b);

    k_sent_lstm<<<B * 2, 128, 0, stream>>>(sl_Whh_f, sl_Whh_b);

    k_attn_pool_doc<S><<<B, 128, 0, stream>>>(ids, sa_W1, sa_b1, sa_W2, sa_b2);

    k_classifier<<<B, 128, 0, stream>>>(cl_W1, cl_b1, cl_W2, cl_b2, (float*)d_out);
}